// Round 1
// baseline (1026.498 us; speedup 1.0000x reference)
//
#include <hip/hip_runtime.h>
#include <math.h>

// Problem constants (from reference)
#define Bq   4
#define Nq   1024
#define Dq   512
#define Hq   8
#define KH   3
#define DHq  64
#define NBH  (Bq*Hq)
#define TS   68   // LDS leading-dim pad: float4-aligned, <=2-way bank conflicts

// ---------------- helpers ----------------

__device__ __forceinline__ unsigned int fkey(float f) {
    unsigned int u = __float_as_uint(f);
    return (u & 0x80000000u) ? ~u : (u | 0x80000000u);
}

// Stage a 64x64 global tile TRANSPOSED into LDS: T[c][r] = src[r*gstride + c]
__device__ __forceinline__ void stageT(const float* src, size_t gstride,
                                       float (*T)[TS], int tid) {
    for (int t = tid; t < 1024; t += 256) {
        int r = t >> 4, c = (t & 15) << 2;
        float4 v = *(const float4*)(src + (size_t)r * gstride + c);
        T[c + 0][r] = v.x; T[c + 1][r] = v.y; T[c + 2][r] = v.z; T[c + 3][r] = v.w;
    }
}

// Stage a 64x64 global tile ROW-MAJOR into LDS: T[r][c] = src[r*gstride + c]
__device__ __forceinline__ void stageR(const float* src, size_t gstride,
                                       float (*T)[TS], int tid) {
    for (int t = tid; t < 1024; t += 256) {
        int r = t >> 4, c = (t & 15) << 2;
        *(float4*)&T[r][c] = *(const float4*)(src + (size_t)r * gstride + c);
    }
}

// 64x64x64 micro-GEMM: acc[i][j] += sum_k At[k][4ty+i] * Bs[k][4tx+j]
__device__ __forceinline__ void mk64(const float (*At)[TS], const float (*Bs)[TS],
                                     int ty, int tx, float acc[4][4]) {
#pragma unroll 8
    for (int k = 0; k < 64; ++k) {
        float4 a  = *(const float4*)&At[k][ty << 2];
        float4 bv = *(const float4*)&Bs[k][tx << 2];
        float av[4] = {a.x, a.y, a.z, a.w};
        float bw[4] = {bv.x, bv.y, bv.z, bv.w};
#pragma unroll
        for (int i = 0; i < 4; ++i)
#pragma unroll
            for (int j = 0; j < 4; ++j)
                acc[i][j] = fmaf(av[i], bw[j], acc[i][j]);
    }
}

// ---------------- kernels ----------------

// S[bh,i,j] = dot(Xh[bh,i,:], Xh[bh,j,:]) / (8 * clip(tau_h, .1, 5))
__global__ __launch_bounds__(256) void score_kernel(const float* __restrict__ X,
                                                    const float* __restrict__ temperature,
                                                    float* __restrict__ S) {
    __shared__ float XiT[64][TS], XjT[64][TS];
    int tid = threadIdx.x;
    int bh = blockIdx.z, b = bh >> 3, h = bh & 7;
    int i0 = blockIdx.y << 6, j0 = blockIdx.x << 6;
    const float* Xb = X + (size_t)b * Nq * Dq + h * DHq;
    stageT(Xb + (size_t)i0 * Dq, Dq, XiT, tid);
    stageT(Xb + (size_t)j0 * Dq, Dq, XjT, tid);
    __syncthreads();
    int ty = tid >> 4, tx = tid & 15;
    float acc[4][4] = {};
    mk64(XiT, XjT, ty, tx, acc);
    float tau = fminf(fmaxf(temperature[h], 0.1f), 5.0f);
    float inv = 1.0f / (8.0f * tau);
    float* Sp = S + ((size_t)bh * Nq + i0 + (ty << 2)) * Nq + j0 + (tx << 2);
#pragma unroll
    for (int ii = 0; ii < 4; ++ii) {
        float4 v = make_float4(acc[ii][0] * inv, acc[ii][1] * inv,
                               acc[ii][2] * inv, acc[ii][3] * inv);
        *(float4*)(Sp + (size_t)ii * Nq) = v;
    }
}

// Per row: exact k-th-largest threshold (radix select), mask (< thresh -> 0), softmax.
__global__ __launch_bounds__(256) void topk_softmax_kernel(float* __restrict__ S,
                                                           const int* __restrict__ layer_idx,
                                                           const int* __restrict__ Lptr) {
    __shared__ float vals[Nq];
    __shared__ unsigned int hist[256];
    __shared__ unsigned int s_prefix;
    __shared__ int s_k;
    __shared__ float s_red[256];
    int tid = threadIdx.x;
    float* Srow = S + (size_t)blockIdx.x * Nq;

    for (int i = tid; i < Nq; i += 256) vals[i] = Srow[i];

    // static top-k size from sparsity schedule (double math to match Python)
    double sp = 0.8 + (0.2 - 0.8) * exp(-3.0 * (double)layer_idx[0] / (double)Lptr[0]);
    int kv = (int)((1.0 - sp) * (double)Nq);
    if (kv < 1) kv = 1;
    __syncthreads();

    unsigned int tk = 0;  // threshold key; 0 keeps everything
    if (kv < Nq) {
        unsigned int prefix = 0;
        int kneed = kv;
#pragma unroll
        for (int pass = 0; pass < 4; ++pass) {
            int shift = 24 - (pass << 3);
            hist[tid] = 0;
            __syncthreads();
            for (int i = tid; i < Nq; i += 256) {
                unsigned int key = fkey(vals[i]);
                bool in = (pass == 0) || ((key >> (shift + 8)) == (prefix >> (shift + 8)));
                if (in) atomicAdd(&hist[(key >> shift) & 255u], 1u);
            }
            __syncthreads();
            if (tid == 0) {
                unsigned int cum = 0; int bsel = 0;
                for (int bi = 255; bi >= 0; --bi) {
                    unsigned int c = hist[bi];
                    if (cum + c >= (unsigned)kneed) { bsel = bi; break; }
                    cum += c;
                }
                s_prefix = prefix | ((unsigned)bsel << shift);
                s_k = kneed - (int)cum;
            }
            __syncthreads();
            prefix = s_prefix; kneed = s_k;
            __syncthreads();
        }
        tk = prefix;  // exact key of the k-th largest value in this row
    }

    // row max
    float m = -INFINITY;
    for (int i = tid; i < Nq; i += 256) m = fmaxf(m, vals[i]);
    s_red[tid] = m; __syncthreads();
    for (int s = 128; s > 0; s >>= 1) {
        if (tid < s) s_red[tid] = fmaxf(s_red[tid], s_red[tid + s]);
        __syncthreads();
    }
    m = s_red[0];
    __syncthreads();

    // masked exp + sum
    float local = 0.f;
    for (int i = tid; i < Nq; i += 256) {
        float v = vals[i];
        bool keep = fkey(v) >= tk;
        float e = keep ? expf(v - m) : 0.0f;
        vals[i] = e;
        local += e;
    }
    s_red[tid] = local; __syncthreads();
    for (int s = 128; s > 0; s >>= 1) {
        if (tid < s) s_red[tid] += s_red[tid + s];
        __syncthreads();
    }
    float invsum = 1.0f / s_red[0];
    for (int i = tid; i < Nq; i += 256) Srow[i] = vals[i] * invsum;
}

// Pout[bh,i,:] = sum_j A[bh,i,j] * Pin[bh,j,:]   (Pin may be Xh-view of X)
__global__ __launch_bounds__(256) void ap_kernel(const float* __restrict__ A,
                                                 const float* __restrict__ Pin,
                                                 const float* __restrict__ X, int fromX,
                                                 float* __restrict__ Pout) {
    __shared__ float AT[64][TS], Ps[64][TS];
    int tid = threadIdx.x;
    int bh = blockIdx.y, b = bh >> 3, h = bh & 7;
    int i0 = blockIdx.x << 6;
    const float* Ab = A + ((size_t)bh * Nq + i0) * Nq;
    const float* Pb; size_t pstr;
    if (fromX) { Pb = X + (size_t)b * Nq * Dq + h * DHq; pstr = Dq; }
    else       { Pb = Pin + (size_t)bh * Nq * DHq;       pstr = DHq; }
    int ty = tid >> 4, tx = tid & 15;
    float acc[4][4] = {};
    for (int jc = 0; jc < Nq / 64; ++jc) {
        stageT(Ab + jc * 64, Nq, AT, tid);
        stageR(Pb + (size_t)jc * 64 * pstr, pstr, Ps, tid);
        __syncthreads();
        mk64(AT, Ps, ty, tx, acc);
        __syncthreads();
    }
    float* Po = Pout + ((size_t)bh * Nq + i0 + (ty << 2)) * DHq + (tx << 2);
#pragma unroll
    for (int ii = 0; ii < 4; ++ii)
        *(float4*)(Po + ii * DHq) = make_float4(acc[ii][0], acc[ii][1], acc[ii][2], acc[ii][3]);
}

// Hacc[b, n, h*DH + e] (+)= alpha[h,k] * sum_d P[bh,n,d] * W_filt[h,k,d,e]
__global__ __launch_bounds__(256) void filt_kernel(const float* __restrict__ Pin,
                                                   const float* __restrict__ X, int fromX,
                                                   const float* __restrict__ W_filt,
                                                   const float* __restrict__ alpha,
                                                   float* __restrict__ Hacc, int khop) {
    __shared__ float PT[64][TS], Ws[64][TS];
    int tid = threadIdx.x;
    int bh = blockIdx.y, b = bh >> 3, h = bh & 7;
    int i0 = blockIdx.x << 6;
    const float* Pb; size_t pstr;
    if (fromX) { Pb = X + (size_t)b * Nq * Dq + h * DHq; pstr = Dq; }
    else       { Pb = Pin + (size_t)bh * Nq * DHq;       pstr = DHq; }
    stageT(Pb + (size_t)i0 * pstr, pstr, PT, tid);
    stageR(W_filt + ((size_t)h * (KH + 1) + khop) * DHq * DHq, DHq, Ws, tid);
    __syncthreads();
    int ty = tid >> 4, tx = tid & 15;
    float acc[4][4] = {};
    mk64(PT, Ws, ty, tx, acc);
    float av = alpha[h * (KH + 1) + khop];
    float* Ho = Hacc + ((size_t)b * Nq + i0 + (ty << 2)) * Dq + h * DHq + (tx << 2);
#pragma unroll
    for (int ii = 0; ii < 4; ++ii) {
        float4 v;
        if (khop > 0) {
            v = *(float4*)(Ho + (size_t)ii * Dq);
            v.x += av * acc[ii][0]; v.y += av * acc[ii][1];
            v.z += av * acc[ii][2]; v.w += av * acc[ii][3];
        } else {
            v = make_float4(av * acc[ii][0], av * acc[ii][1],
                            av * acc[ii][2], av * acc[ii][3]);
        }
        *(float4*)(Ho + (size_t)ii * Dq) = v;
    }
}

// out[i,j] = b_proj[j] + sum_d Hacc[i,d] * W_proj[j,d]
__global__ __launch_bounds__(256) void proj_kernel(const float* __restrict__ Hacc,
                                                   const float* __restrict__ Wp,
                                                   const float* __restrict__ bp,
                                                   float* __restrict__ out) {
    __shared__ float HT[64][TS], WT[64][TS];
    int tid = threadIdx.x;
    int i0 = blockIdx.y << 6;  // rows over B*N = 4096
    int j0 = blockIdx.x << 6;  // cols over D
    int ty = tid >> 4, tx = tid & 15;
    float acc[4][4] = {};
    for (int dc = 0; dc < Dq / 64; ++dc) {
        stageT(Hacc + (size_t)i0 * Dq + dc * 64, Dq, HT, tid);
        stageT(Wp + (size_t)j0 * Dq + dc * 64, Dq, WT, tid);
        __syncthreads();
        mk64(HT, WT, ty, tx, acc);
        __syncthreads();
    }
    float4 bias = *(const float4*)(bp + j0 + (tx << 2));
    float* Op = out + ((size_t)(i0 + (ty << 2))) * Dq + j0 + (tx << 2);
#pragma unroll
    for (int ii = 0; ii < 4; ++ii) {
        float4 v = make_float4(acc[ii][0] + bias.x, acc[ii][1] + bias.y,
                               acc[ii][2] + bias.z, acc[ii][3] + bias.w);
        *(float4*)(Op + (size_t)ii * Dq) = v;
    }
}

// ---------------- launch ----------------

extern "C" void kernel_launch(void* const* d_in, const int* in_sizes, int n_in,
                              void* d_out, int out_size, void* d_ws, size_t ws_size,
                              hipStream_t stream) {
    (void)in_sizes; (void)n_in; (void)out_size; (void)ws_size;
    const float* X           = (const float*)d_in[0];
    const float* temperature = (const float*)d_in[1];
    const float* W_filt      = (const float*)d_in[2];
    const float* alpha       = (const float*)d_in[3];
    const float* W_proj      = (const float*)d_in[4];
    const float* b_proj      = (const float*)d_in[5];
    const int*   layer_idx   = (const int*)d_in[6];
    const int*   Lp          = (const int*)d_in[7];
    float* out = (float*)d_out;

    float* S    = (float*)d_ws;                      // [32,1024,1024] f32 = 128 MiB
    float* P1   = S  + (size_t)NBH * Nq * Nq;        // [32,1024,64]
    float* P2   = P1 + (size_t)NBH * Nq * DHq;       // [32,1024,64]
    float* Hacc = P2 + (size_t)NBH * Nq * DHq;       // [4,1024,512]

    dim3 blk(256);
    score_kernel<<<dim3(16, 16, 32), blk, 0, stream>>>(X, temperature, S);
    topk_softmax_kernel<<<dim3(NBH * Nq), blk, 0, stream>>>(S, layer_idx, Lp);

    // hop 0 (P = Xh), initializes Hacc
    filt_kernel<<<dim3(16, 32), blk, 0, stream>>>(nullptr, X, 1, W_filt, alpha, Hacc, 0);
    // hop 1: P1 = A @ Xh
    ap_kernel<<<dim3(16, 32), blk, 0, stream>>>(S, nullptr, X, 1, P1);
    filt_kernel<<<dim3(16, 32), blk, 0, stream>>>(P1, nullptr, 0, W_filt, alpha, Hacc, 1);
    // hop 2: P2 = A @ P1
    ap_kernel<<<dim3(16, 32), blk, 0, stream>>>(S, P1, nullptr, 0, P2);
    filt_kernel<<<dim3(16, 32), blk, 0, stream>>>(P2, nullptr, 0, W_filt, alpha, Hacc, 2);
    // hop 3: P1 = A @ P2
    ap_kernel<<<dim3(16, 32), blk, 0, stream>>>(S, P2, nullptr, 0, P1);
    filt_kernel<<<dim3(16, 32), blk, 0, stream>>>(P1, nullptr, 0, W_filt, alpha, Hacc, 3);

    proj_kernel<<<dim3(8, 64), blk, 0, stream>>>(Hacc, W_proj, b_proj, out);
}

// Round 2
// 540.207 us; speedup vs baseline: 1.9002x; 1.9002x over previous
//
#include <hip/hip_runtime.h>
#include <math.h>

// Problem constants (from reference)
#define Bq   4
#define Nq   1024
#define Dq   512
#define Hq   8
#define KH   3
#define DHq  64
#define NBH  (Bq*Hq)
#define TS   68   // LDS leading-dim pad: float4-aligned

// ---------------- helpers ----------------

__device__ __forceinline__ unsigned int fkey(float f) {
    unsigned int u = __float_as_uint(f);
    return (u & 0x80000000u) ? ~u : (u | 0x80000000u);
}

// load a 64x64 tile into 4 float4 regs (coalesced)
__device__ __forceinline__ void tile_load(const float* src, size_t gstride, int tid, float4 r[4]) {
#pragma unroll
    for (int u = 0; u < 4; ++u) {
        int t = tid + (u << 8);
        int rr = t >> 4, c = (t & 15) << 2;
        r[u] = *(const float4*)(src + (size_t)rr * gstride + c);
    }
}
// store regs into LDS transposed: T[c][r]
__device__ __forceinline__ void tile_storeT(float (*T)[TS], int tid, const float4 r[4]) {
#pragma unroll
    for (int u = 0; u < 4; ++u) {
        int t = tid + (u << 8);
        int rr = t >> 4, c = (t & 15) << 2;
        T[c + 0][rr] = r[u].x; T[c + 1][rr] = r[u].y;
        T[c + 2][rr] = r[u].z; T[c + 3][rr] = r[u].w;
    }
}
// store regs into LDS row-major: T[r][c]
__device__ __forceinline__ void tile_storeR(float (*T)[TS], int tid, const float4 r[4]) {
#pragma unroll
    for (int u = 0; u < 4; ++u) {
        int t = tid + (u << 8);
        int rr = t >> 4, c = (t & 15) << 2;
        *(float4*)&T[rr][c] = r[u];
    }
}

// 64x64x64 micro-GEMM: acc[i][j] += sum_k At[k][4ty+i] * Bs[k][4tx+j]
__device__ __forceinline__ void mk64(const float (*At)[TS], const float (*Bs)[TS],
                                     int ty, int tx, float acc[4][4]) {
#pragma unroll 8
    for (int k = 0; k < 64; ++k) {
        float4 a  = *(const float4*)&At[k][ty << 2];
        float4 bv = *(const float4*)&Bs[k][tx << 2];
        float av[4] = {a.x, a.y, a.z, a.w};
        float bw[4] = {bv.x, bv.y, bv.z, bv.w};
#pragma unroll
        for (int i = 0; i < 4; ++i)
#pragma unroll
            for (int j = 0; j < 4; ++j)
                acc[i][j] = fmaf(av[i], bw[j], acc[i][j]);
    }
}

// ---------------- kernels ----------------

// S[bh,i,j] = dot(Xh[bh,i,:], Xh[bh,j,:]) / (8 * clip(tau_h, .1, 5))
__global__ __launch_bounds__(256) void score_kernel(const float* __restrict__ X,
                                                    const float* __restrict__ temperature,
                                                    float* __restrict__ S) {
    __shared__ float XiT[64][TS], XjT[64][TS];
    int tid = threadIdx.x;
    int bh = blockIdx.z, b = bh >> 3, h = bh & 7;
    int i0 = blockIdx.y << 6, j0 = blockIdx.x << 6;
    const float* Xb = X + (size_t)b * Nq * Dq + h * DHq;
    float4 ri[4], rj[4];
    tile_load(Xb + (size_t)i0 * Dq, Dq, tid, ri);
    tile_load(Xb + (size_t)j0 * Dq, Dq, tid, rj);
    tile_storeT(XiT, tid, ri);
    tile_storeT(XjT, tid, rj);
    __syncthreads();
    int ty = tid >> 4, tx = tid & 15;
    float acc[4][4] = {};
    mk64(XiT, XjT, ty, tx, acc);
    float tau = fminf(fmaxf(temperature[h], 0.1f), 5.0f);
    float inv = 1.0f / (8.0f * tau);
    float* Sp = S + ((size_t)bh * Nq + i0 + (ty << 2)) * Nq + j0 + (tx << 2);
#pragma unroll
    for (int ii = 0; ii < 4; ++ii) {
        float4 v = make_float4(acc[ii][0] * inv, acc[ii][1] * inv,
                               acc[ii][2] * inv, acc[ii][3] * inv);
        *(float4*)(Sp + (size_t)ii * Nq) = v;
    }
}

// One row per 64-lane wave: values in registers, per-wave radix select (exact
// k-th largest), then masked softmax. No barriers — waves are independent.
__global__ __launch_bounds__(256) void topk_softmax_kernel(float* __restrict__ S,
                                                           const int* __restrict__ layer_idx,
                                                           const int* __restrict__ Lptr) {
    __shared__ unsigned int wh[4][256];
    int tid = threadIdx.x;
    int w = tid >> 6, lane = tid & 63;
    float* Srow = S + ((size_t)blockIdx.x * 4 + w) * Nq;
    float4* S4 = (float4*)Srow;

    float v[16]; unsigned int keys[16];
#pragma unroll
    for (int j = 0; j < 4; ++j) {
        float4 q = S4[(j << 6) + lane];
        v[j * 4 + 0] = q.x; v[j * 4 + 1] = q.y;
        v[j * 4 + 2] = q.z; v[j * 4 + 3] = q.w;
    }
#pragma unroll
    for (int i = 0; i < 16; ++i) keys[i] = fkey(v[i]);

    // static top-k size from sparsity schedule (double math to match Python)
    double sp = 0.8 + (0.2 - 0.8) * exp(-3.0 * (double)layer_idx[0] / (double)Lptr[0]);
    int kv = (int)((1.0 - sp) * (double)Nq);
    if (kv < 1) kv = 1;

    unsigned int tk = 0;  // 0 keeps everything
    if (kv < Nq) {
        unsigned int prefix = 0;
        unsigned int kneed = (unsigned)kv;
#pragma unroll
        for (int pass = 0; pass < 4; ++pass) {
            const int shift = 24 - (pass << 3);
            // zero own-wave histogram (wave-private; same-wave DS ops are in order)
            wh[w][lane] = 0; wh[w][lane + 64] = 0;
            wh[w][lane + 128] = 0; wh[w][lane + 192] = 0;
            int hs = (pass == 0) ? 0 : (shift + 8);
            unsigned int msk = (pass == 0) ? 0u : (0xFFFFFFFFu << hs);
#pragma unroll
            for (int i = 0; i < 16; ++i) {
                if ((keys[i] & msk) == (prefix & msk))
                    atomicAdd(&wh[w][(keys[i] >> shift) & 255u], 1u);
            }
            // lane l owns 4 descending bins: 255-4l .. 252-4l
            uint4 u4 = *((uint4*)&wh[w][252 - (lane << 2)]);
            unsigned c0 = u4.w, c1 = u4.z, c2 = u4.y, c3 = u4.x;
            unsigned p1 = c0 + c1, p2 = p1 + c2, p3 = p2 + c3;
            unsigned inc = p3;
#pragma unroll
            for (int off = 1; off < 64; off <<= 1) {
                unsigned x = __shfl_up(inc, off);
                if (lane >= off) inc += x;
            }
            unsigned excl = inc - p3;
            bool has = (excl < kneed) && (inc >= kneed);
            unsigned long long bal = __ballot(has);
            int src = __ffsll(bal) - 1;  // exactly one lane crosses kneed
            int digit = 0; int rem = 0;
            if (has) {
                if (excl + c0 >= kneed)      { digit = 255 - (lane << 2); rem = (int)(kneed - excl); }
                else if (excl + p1 >= kneed) { digit = 254 - (lane << 2); rem = (int)(kneed - excl - c0); }
                else if (excl + p2 >= kneed) { digit = 253 - (lane << 2); rem = (int)(kneed - excl - p1); }
                else                         { digit = 252 - (lane << 2); rem = (int)(kneed - excl - p2); }
            }
            digit = __shfl(digit, src);
            rem   = __shfl(rem, src);
            prefix |= (unsigned)digit << shift;
            kneed = (unsigned)rem;
        }
        tk = prefix;  // exact key of the k-th largest value in this row
    }

    // masked softmax, all in registers
    float m = v[0];
#pragma unroll
    for (int i = 1; i < 16; ++i) m = fmaxf(m, v[i]);
#pragma unroll
    for (int off = 32; off; off >>= 1) m = fmaxf(m, __shfl_xor(m, off));
    float sum = 0.f;
#pragma unroll
    for (int i = 0; i < 16; ++i) {
        float e = (keys[i] >= tk) ? __expf(v[i] - m) : 0.0f;
        v[i] = e; sum += e;
    }
#pragma unroll
    for (int off = 32; off; off >>= 1) sum += __shfl_xor(sum, off);
    float inv = 1.0f / sum;
#pragma unroll
    for (int j = 0; j < 4; ++j) {
        float4 q = make_float4(v[j * 4 + 0] * inv, v[j * 4 + 1] * inv,
                               v[j * 4 + 2] * inv, v[j * 4 + 3] * inv);
        S4[(j << 6) + lane] = q;
    }
}

// hop 0 filter: Hacc = alpha[h,0] * (Xh @ W_filt[h,0])   (initializes Hacc)
__global__ __launch_bounds__(256) void filt0_kernel(const float* __restrict__ X,
                                                    const float* __restrict__ W_filt,
                                                    const float* __restrict__ alpha,
                                                    float* __restrict__ Hacc) {
    __shared__ float PT[64][TS], Ws[64][TS];
    int tid = threadIdx.x;
    int bh = blockIdx.y, b = bh >> 3, h = bh & 7;
    int i0 = blockIdx.x << 6;
    const float* Pb = X + (size_t)b * Nq * Dq + h * DHq;
    float4 rp[4], rw[4];
    tile_load(Pb + (size_t)i0 * Dq, Dq, tid, rp);
    tile_load(W_filt + (size_t)h * (KH + 1) * DHq * DHq, DHq, tid, rw);
    tile_storeT(PT, tid, rp);
    tile_storeR(Ws, tid, rw);
    __syncthreads();
    int ty = tid >> 4, tx = tid & 15;
    float acc[4][4] = {};
    mk64(PT, Ws, ty, tx, acc);
    float av = alpha[h * (KH + 1)];
    float* Ho = Hacc + ((size_t)b * Nq + i0 + (ty << 2)) * Dq + h * DHq + (tx << 2);
#pragma unroll
    for (int ii = 0; ii < 4; ++ii)
        *(float4*)(Ho + (size_t)ii * Dq) = make_float4(av * acc[ii][0], av * acc[ii][1],
                                                       av * acc[ii][2], av * acc[ii][3]);
}

// Fused hop: Pout = A @ Pin (per bh); Hacc += alpha[h,khop] * (Pout @ W_filt[h,khop]).
// Register-prefetch double buffering hides global latency under mk64.
__global__ __launch_bounds__(256) void apf_kernel(const float* __restrict__ A,
                                                  const float* __restrict__ Pin,
                                                  const float* __restrict__ X, int fromX,
                                                  float* __restrict__ Pout, int writeP,
                                                  const float* __restrict__ W_filt,
                                                  const float* __restrict__ alpha,
                                                  float* __restrict__ Hacc, int khop) {
    __shared__ float AT[64][TS], Ps[64][TS];
    int tid = threadIdx.x;
    int bh = blockIdx.y, b = bh >> 3, h = bh & 7;
    int i0 = blockIdx.x << 6;
    const float* Ab = A + ((size_t)bh * Nq + i0) * Nq;
    const float* Pb; size_t pstr;
    if (fromX) { Pb = X + (size_t)b * Nq * Dq + h * DHq; pstr = Dq; }
    else       { Pb = Pin + (size_t)bh * Nq * DHq;       pstr = DHq; }
    int ty = tid >> 4, tx = tid & 15;

    float4 ra[4], rp[4];
    tile_load(Ab, Nq, tid, ra);
    tile_load(Pb, pstr, tid, rp);
    tile_storeT(AT, tid, ra);
    tile_storeR(Ps, tid, rp);
    __syncthreads();

    float acc[4][4] = {};
    for (int jc = 0; jc < 16; ++jc) {
        if (jc < 15) {  // issue next-tile loads; latency hides under mk64
            tile_load(Ab + (jc + 1) * 64, Nq, tid, ra);
            tile_load(Pb + (size_t)(jc + 1) * 64 * pstr, pstr, tid, rp);
        }
        mk64(AT, Ps, ty, tx, acc);
        __syncthreads();
        if (jc < 15) {
            tile_storeT(AT, tid, ra);
            tile_storeR(Ps, tid, rp);
            __syncthreads();
        }
    }

    // ---- fused filter ----
    float4 rw[4];
    tile_load(W_filt + ((size_t)h * (KH + 1) + khop) * DHq * DHq, DHq, tid, rw);
    // write P-block transposed into AT: AT[d][n]
#pragma unroll
    for (int i = 0; i < 4; ++i)
#pragma unroll
        for (int j = 0; j < 4; ++j)
            AT[(tx << 2) + j][(ty << 2) + i] = acc[i][j];
    if (writeP) {
        float* Po = Pout + ((size_t)bh * Nq + i0 + (ty << 2)) * DHq + (tx << 2);
#pragma unroll
        for (int ii = 0; ii < 4; ++ii)
            *(float4*)(Po + ii * DHq) = make_float4(acc[ii][0], acc[ii][1],
                                                    acc[ii][2], acc[ii][3]);
    }
    tile_storeR(Ps, tid, rw);
    __syncthreads();
    float hacc[4][4] = {};
    mk64(AT, Ps, ty, tx, hacc);
    float av = alpha[h * (KH + 1) + khop];
    float* Ho = Hacc + ((size_t)b * Nq + i0 + (ty << 2)) * Dq + h * DHq + (tx << 2);
#pragma unroll
    for (int ii = 0; ii < 4; ++ii) {
        float4 hv = *(float4*)(Ho + (size_t)ii * Dq);
        hv.x += av * hacc[ii][0]; hv.y += av * hacc[ii][1];
        hv.z += av * hacc[ii][2]; hv.w += av * hacc[ii][3];
        *(float4*)(Ho + (size_t)ii * Dq) = hv;
    }
}

// out[i,j] = b_proj[j] + sum_d Hacc[i,d] * W_proj[j,d]  (reg-prefetch dbuf)
__global__ __launch_bounds__(256) void proj_kernel(const float* __restrict__ Hacc,
                                                   const float* __restrict__ Wp,
                                                   const float* __restrict__ bp,
                                                   float* __restrict__ out) {
    __shared__ float HT[64][TS], WT[64][TS];
    int tid = threadIdx.x;
    int i0 = blockIdx.y << 6;  // rows over B*N = 4096
    int j0 = blockIdx.x << 6;  // cols over D
    int ty = tid >> 4, tx = tid & 15;
    float4 rh[4], rw[4];
    tile_load(Hacc + (size_t)i0 * Dq, Dq, tid, rh);
    tile_load(Wp + (size_t)j0 * Dq, Dq, tid, rw);
    tile_storeT(HT, tid, rh);
    tile_storeT(WT, tid, rw);
    __syncthreads();
    float acc[4][4] = {};
    for (int dc = 0; dc < Dq / 64; ++dc) {
        if (dc < 7) {
            tile_load(Hacc + (size_t)i0 * Dq + (dc + 1) * 64, Dq, tid, rh);
            tile_load(Wp + (size_t)j0 * Dq + (dc + 1) * 64, Dq, tid, rw);
        }
        mk64(HT, WT, ty, tx, acc);
        __syncthreads();
        if (dc < 7) {
            tile_storeT(HT, tid, rh);
            tile_storeT(WT, tid, rw);
            __syncthreads();
        }
    }
    float4 bias = *(const float4*)(bp + j0 + (tx << 2));
    float* Op = out + ((size_t)(i0 + (ty << 2))) * Dq + j0 + (tx << 2);
#pragma unroll
    for (int ii = 0; ii < 4; ++ii) {
        float4 v = make_float4(acc[ii][0] + bias.x, acc[ii][1] + bias.y,
                               acc[ii][2] + bias.z, acc[ii][3] + bias.w);
        *(float4*)(Op + (size_t)ii * Dq) = v;
    }
}

// ---------------- launch ----------------

extern "C" void kernel_launch(void* const* d_in, const int* in_sizes, int n_in,
                              void* d_out, int out_size, void* d_ws, size_t ws_size,
                              hipStream_t stream) {
    (void)in_sizes; (void)n_in; (void)out_size; (void)ws_size;
    const float* X           = (const float*)d_in[0];
    const float* temperature = (const float*)d_in[1];
    const float* W_filt      = (const float*)d_in[2];
    const float* alpha       = (const float*)d_in[3];
    const float* W_proj      = (const float*)d_in[4];
    const float* b_proj      = (const float*)d_in[5];
    const int*   layer_idx   = (const int*)d_in[6];
    const int*   Lp          = (const int*)d_in[7];
    float* out = (float*)d_out;

    float* S    = (float*)d_ws;                      // [32,1024,1024] f32 = 128 MiB
    float* P1   = S  + (size_t)NBH * Nq * Nq;        // [32,1024,64]
    float* P2   = P1 + (size_t)NBH * Nq * DHq;       // [32,1024,64]
    float* Hacc = P2 + (size_t)NBH * Nq * DHq;       // [4,1024,512]

    dim3 blk(256);
    score_kernel<<<dim3(16, 16, 32), blk, 0, stream>>>(X, temperature, S);
    topk_softmax_kernel<<<dim3(NBH * Nq / 4), blk, 0, stream>>>(S, layer_idx, Lp);

    filt0_kernel<<<dim3(16, 32), blk, 0, stream>>>(X, W_filt, alpha, Hacc);
    // hop 1: P1 = A @ Xh ; Hacc += a1 * P1 @ W1
    apf_kernel<<<dim3(16, 32), blk, 0, stream>>>(S, nullptr, X, 1, P1, 1, W_filt, alpha, Hacc, 1);
    // hop 2: P2 = A @ P1 ; Hacc += a2 * P2 @ W2
    apf_kernel<<<dim3(16, 32), blk, 0, stream>>>(S, P1, nullptr, 0, P2, 1, W_filt, alpha, Hacc, 2);
    // hop 3: Hacc += a3 * (A @ P2) @ W3  (P store skipped)
    apf_kernel<<<dim3(16, 32), blk, 0, stream>>>(S, P2, nullptr, 0, P1, 0, W_filt, alpha, Hacc, 3);

    proj_kernel<<<dim3(8, 64), blk, 0, stream>>>(Hacc, W_proj, b_proj, out);
}

// Round 3
// 332.749 us; speedup vs baseline: 3.0849x; 1.6235x over previous
//
#include <hip/hip_runtime.h>
#include <math.h>

// Problem constants
#define Nq   1024
#define Dq   512
#define Hq   8
#define KH   3
#define DHq  64
#define NBH  32

typedef __attribute__((ext_vector_type(8))) __bf16 bf16x8;
typedef __attribute__((ext_vector_type(4))) float f32x4;

#define LDA 136   // LDS row stride (ushorts) for 128-wide K tiles (272 B = 17*16)
#define LDW 72    // LDS row stride (ushorts) for 64-wide K tiles (144 B = 9*16)

// ---------------- helpers ----------------

__device__ __forceinline__ unsigned short f2bf(float f) {  // RNE f32->bf16
    unsigned int u = __float_as_uint(f);
    u += 0x7FFFu + ((u >> 16) & 1u);
    return (unsigned short)(u >> 16);
}
__device__ __forceinline__ float bf2f(unsigned short b) {
    return __uint_as_float(((unsigned int)b) << 16);
}
__device__ __forceinline__ unsigned int fkey(float f) {
    unsigned int u = __float_as_uint(f);
    return (u & 0x80000000u) ? ~u : (u | 0x80000000u);
}
__device__ __forceinline__ uint2 pack4(float4 v) {
    return make_uint2((unsigned)f2bf(v.x) | ((unsigned)f2bf(v.y) << 16),
                      (unsigned)f2bf(v.z) | ((unsigned)f2bf(v.w) << 16));
}
__device__ __forceinline__ f32x4 fzero() { f32x4 z = {0.f, 0.f, 0.f, 0.f}; return z; }

// MFMA fragment addressing (16x16x32 bf16):
//  A-frag: lane l holds A[row=l&15][k=(l>>4)*8 + j]  -> row-major [m][k] LDS, b128 read
//  B-frag: lane l holds B[k=(l>>4)*8 + j][col=l&15]  -> store as [n][k] LDS, same read formula
//  C/D:    reg r -> C[row=(l>>4)*4+r][col=l&15]

// ---------------- kernels ----------------

// X f32 -> Xn bf16 [bh][1024][64] (n-major) and Xt bf16 [bh][64][1024] (d-major)
__global__ __launch_bounds__(256) void xcast_kernel(const float* __restrict__ X,
                                                    unsigned short* __restrict__ Xn,
                                                    unsigned short* __restrict__ Xt) {
    __shared__ float T[64][68];
    int tid = threadIdx.x;
    int bh = blockIdx.y, b = bh >> 3, h = bh & 7;
    int n0 = blockIdx.x << 6;
    const float* Xg = X + ((size_t)b * Nq + n0) * Dq + h * DHq;
#pragma unroll
    for (int u = 0; u < 4; ++u) {
        int idx = tid + (u << 8);
        int r = idx >> 4, c4 = (idx & 15) << 2;
        float4 v = *(const float4*)&Xg[(size_t)r * Dq + c4];
        *(uint2*)&Xn[((size_t)bh * Nq + n0 + r) * DHq + c4] = pack4(v);
        T[c4 + 0][r] = v.x; T[c4 + 1][r] = v.y; T[c4 + 2][r] = v.z; T[c4 + 3][r] = v.w;
    }
    __syncthreads();
#pragma unroll
    for (int u = 0; u < 4; ++u) {
        int idx = tid + (u << 8);
        int d = idx >> 4, n4 = (idx & 15) << 2;
        float4 v = make_float4(T[d][n4], T[d][n4 + 1], T[d][n4 + 2], T[d][n4 + 3]);
        *(uint2*)&Xt[((size_t)bh * DHq + d) * Nq + n0 + n4] = pack4(v);
    }
}

// S[bh,i,j] = dot(Xh[i],Xh[j]) / (8*clip(tau)), bf16 MFMA, S stored bf16
__global__ __launch_bounds__(256) void score_mfma(const unsigned short* __restrict__ Xn,
                                                  const float* __restrict__ temperature,
                                                  unsigned short* __restrict__ Sbf) {
    __shared__ unsigned short Xi[64 * LDW], Xj[64 * LDW];
    int tid = threadIdx.x, lane = tid & 63, w = tid >> 6;
    int bh = blockIdx.z, i0 = blockIdx.y << 6, j0 = blockIdx.x << 6;
    const unsigned short* Xb = Xn + (size_t)bh * Nq * DHq;
    {
        int row = tid >> 3, o = (tid & 7) << 3;
#pragma unroll
        for (int u = 0; u < 2; ++u) {
            int r = row + (u << 5);
            *(uint4*)&Xi[r * LDW + o] = *(const uint4*)&Xb[(size_t)(i0 + r) * DHq + o];
            *(uint4*)&Xj[r * LDW + o] = *(const uint4*)&Xb[(size_t)(j0 + r) * DHq + o];
        }
    }
    __syncthreads();
    f32x4 acc[4] = {fzero(), fzero(), fzero(), fzero()};
    int brow = lane & 15, ko = (lane >> 4) << 3;
    const unsigned short* Afr = &Xi[((w << 4) + brow) * LDW + ko];
#pragma unroll
    for (int ks = 0; ks < 2; ++ks) {
        bf16x8 af = *(const bf16x8*)(Afr + (ks << 5));
#pragma unroll
        for (int nt = 0; nt < 4; ++nt) {
            bf16x8 bfv = *(const bf16x8*)&Xj[((nt << 4) + brow) * LDW + (ks << 5) + ko];
            acc[nt] = __builtin_amdgcn_mfma_f32_16x16x32_bf16(af, bfv, acc[nt], 0, 0, 0);
        }
    }
    float tau = fminf(fmaxf(temperature[bh & 7], 0.1f), 5.0f);
    float inv = 1.0f / (8.0f * tau);
    int nrow = (w << 4) + ((lane >> 4) << 2);
    unsigned short* Sp = Sbf + ((size_t)bh * Nq + i0 + nrow) * Nq + j0;
#pragma unroll
    for (int nt = 0; nt < 4; ++nt)
#pragma unroll
        for (int r = 0; r < 4; ++r)
            Sp[(size_t)r * Nq + (nt << 4) + brow] = f2bf(acc[nt][r] * inv);
}

// One row per wave: exact radix-select k-th largest + masked softmax; bf16 in/out in place.
__global__ __launch_bounds__(256) void topk_softmax_kernel(unsigned short* __restrict__ Sbf,
                                                           const int* __restrict__ layer_idx,
                                                           const int* __restrict__ Lptr) {
    __shared__ unsigned int wh[4][256];
    int tid = threadIdx.x;
    int w = tid >> 6, lane = tid & 63;
    unsigned short* Srow = Sbf + ((size_t)blockIdx.x * 4 + w) * Nq;
    uint4 q0 = ((const uint4*)Srow)[lane * 2];
    uint4 q1 = ((const uint4*)Srow)[lane * 2 + 1];
    float v[16]; unsigned int keys[16];
    {
        unsigned int ww[8] = {q0.x, q0.y, q0.z, q0.w, q1.x, q1.y, q1.z, q1.w};
#pragma unroll
        for (int i = 0; i < 8; ++i) {
            v[2 * i]     = __uint_as_float(ww[i] << 16);
            v[2 * i + 1] = __uint_as_float(ww[i] & 0xFFFF0000u);
        }
    }
#pragma unroll
    for (int i = 0; i < 16; ++i) keys[i] = fkey(v[i]);

    double sp = 0.8 + (0.2 - 0.8) * exp(-3.0 * (double)layer_idx[0] / (double)Lptr[0]);
    int kv = (int)((1.0 - sp) * (double)Nq);
    if (kv < 1) kv = 1;

    unsigned int tk = 0;
    if (kv < Nq) {
        unsigned int prefix = 0;
        unsigned int kneed = (unsigned)kv;
#pragma unroll
        for (int pass = 0; pass < 4; ++pass) {
            const int shift = 24 - (pass << 3);
            wh[w][lane] = 0; wh[w][lane + 64] = 0;
            wh[w][lane + 128] = 0; wh[w][lane + 192] = 0;
            int hs = (pass == 0) ? 0 : (shift + 8);
            unsigned int msk = (pass == 0) ? 0u : (0xFFFFFFFFu << hs);
#pragma unroll
            for (int i = 0; i < 16; ++i) {
                if ((keys[i] & msk) == (prefix & msk))
                    atomicAdd(&wh[w][(keys[i] >> shift) & 255u], 1u);
            }
            uint4 u4 = *((uint4*)&wh[w][252 - (lane << 2)]);
            unsigned c0 = u4.w, c1 = u4.z, c2 = u4.y, c3 = u4.x;
            unsigned p1 = c0 + c1, p2 = p1 + c2, p3 = p2 + c3;
            unsigned inc = p3;
#pragma unroll
            for (int off = 1; off < 64; off <<= 1) {
                unsigned x = __shfl_up(inc, off);
                if (lane >= off) inc += x;
            }
            unsigned excl = inc - p3;
            bool has = (excl < kneed) && (inc >= kneed);
            unsigned long long bal = __ballot(has);
            int src = __ffsll(bal) - 1;
            int digit = 0; int rem = 0;
            if (has) {
                if (excl + c0 >= kneed)      { digit = 255 - (lane << 2); rem = (int)(kneed - excl); }
                else if (excl + p1 >= kneed) { digit = 254 - (lane << 2); rem = (int)(kneed - excl - c0); }
                else if (excl + p2 >= kneed) { digit = 253 - (lane << 2); rem = (int)(kneed - excl - p1); }
                else                         { digit = 252 - (lane << 2); rem = (int)(kneed - excl - p2); }
            }
            digit = __shfl(digit, src);
            rem   = __shfl(rem, src);
            prefix |= (unsigned)digit << shift;
            kneed = (unsigned)rem;
        }
        tk = prefix;
    }

    float m = v[0];
#pragma unroll
    for (int i = 1; i < 16; ++i) m = fmaxf(m, v[i]);
#pragma unroll
    for (int off = 32; off; off >>= 1) m = fmaxf(m, __shfl_xor(m, off));
    float sum = 0.f;
#pragma unroll
    for (int i = 0; i < 16; ++i) {
        float e = (keys[i] >= tk) ? __expf(v[i] - m) : 0.0f;
        v[i] = e; sum += e;
    }
#pragma unroll
    for (int off = 32; off; off >>= 1) sum += __shfl_xor(sum, off);
    float inv = 1.0f / sum;
    unsigned int ow[8];
#pragma unroll
    for (int i = 0; i < 8; ++i)
        ow[i] = (unsigned)f2bf(v[2 * i] * inv) | ((unsigned)f2bf(v[2 * i + 1] * inv) << 16);
    ((uint4*)Srow)[lane * 2]     = make_uint4(ow[0], ow[1], ow[2], ow[3]);
    ((uint4*)Srow)[lane * 2 + 1] = make_uint4(ow[4], ow[5], ow[6], ow[7]);
}

// hop 0: Hacc = alpha[h,0] * (Xh @ W_filt[h,0])  via MFMA (initializes Hacc)
__global__ __launch_bounds__(256) void filt0_mfma(const unsigned short* __restrict__ Xn,
                                                  const float* __restrict__ W_filt,
                                                  const float* __restrict__ alpha,
                                                  float* __restrict__ Hacc) {
    __shared__ unsigned short PnL[64 * LDW], WtL[64 * LDW];
    int tid = threadIdx.x, lane = tid & 63, w = tid >> 6;
    int bh = blockIdx.y, b = bh >> 3, h = bh & 7;
    int n0 = blockIdx.x << 6;
    {
        int row = tid >> 3, o = (tid & 7) << 3;
        const unsigned short* Xb = Xn + ((size_t)bh * Nq + n0) * DHq;
#pragma unroll
        for (int u = 0; u < 2; ++u) {
            int r = row + (u << 5);
            *(uint4*)&PnL[r * LDW + o] = *(const uint4*)&Xb[(size_t)r * DHq + o];
        }
    }
    const float* Wg = W_filt + (size_t)h * (KH + 1) * DHq * DHq;
    for (int u = tid; u < 1024; u += 256) {
        int d = u >> 4, e4 = (u & 15) << 2;
        float4 wv = *(const float4*)&Wg[d * 64 + e4];
        WtL[(e4 + 0) * LDW + d] = f2bf(wv.x);
        WtL[(e4 + 1) * LDW + d] = f2bf(wv.y);
        WtL[(e4 + 2) * LDW + d] = f2bf(wv.z);
        WtL[(e4 + 3) * LDW + d] = f2bf(wv.w);
    }
    __syncthreads();
    f32x4 acc[4] = {fzero(), fzero(), fzero(), fzero()};
    int brow = lane & 15, ko = (lane >> 4) << 3;
    const unsigned short* Afr = &PnL[((w << 4) + brow) * LDW + ko];
#pragma unroll
    for (int ks = 0; ks < 2; ++ks) {
        bf16x8 af = *(const bf16x8*)(Afr + (ks << 5));
#pragma unroll
        for (int nt = 0; nt < 4; ++nt) {
            bf16x8 bfv = *(const bf16x8*)&WtL[((nt << 4) + brow) * LDW + (ks << 5) + ko];
            acc[nt] = __builtin_amdgcn_mfma_f32_16x16x32_bf16(af, bfv, acc[nt], 0, 0, 0);
        }
    }
    float av = alpha[h * (KH + 1)];
    int nrow = (w << 4) + ((lane >> 4) << 2);
    float* Ho = Hacc + ((size_t)b * Nq + n0 + nrow) * Dq + h * DHq;
#pragma unroll
    for (int nt = 0; nt < 4; ++nt)
#pragma unroll
        for (int r = 0; r < 4; ++r)
            Ho[(size_t)r * Dq + (nt << 4) + brow] = av * acc[nt][r];
}

// Fused hop: Pn = A @ Pprev (A bf16 [bh][1024][1024], Pprev^T bf16 [bh][64][1024]);
// optionally write Pn^T bf16; then Hacc += alpha[h,khop] * Pn @ W_filt[h,khop].
__global__ __launch_bounds__(256) void apf_mfma(const unsigned short* __restrict__ Abf,
                                                const unsigned short* __restrict__ Ptin,
                                                unsigned short* __restrict__ Ptout, int writeP,
                                                const float* __restrict__ W_filt,
                                                const float* __restrict__ alpha,
                                                float* __restrict__ Hacc, int khop) {
    __shared__ unsigned short A_lds[64 * LDA];
    __shared__ unsigned short P_lds[64 * LDA];
    int tid = threadIdx.x, lane = tid & 63, w = tid >> 6;
    int bh = blockIdx.y, b = bh >> 3, h = bh & 7;
    int n0 = blockIdx.x << 6;
    const unsigned short* Ag = Abf + ((size_t)bh * Nq + n0) * Nq;
    const unsigned short* Pg = Ptin + (size_t)bh * DHq * Nq;
    int r0 = tid >> 4, oo = (tid & 15) << 3;

    uint4 ra[4], rp[4];
#pragma unroll
    for (int u = 0; u < 4; ++u) {
        ra[u] = *(const uint4*)&Ag[(size_t)(r0 + (u << 4)) * Nq + oo];
        rp[u] = *(const uint4*)&Pg[(size_t)(r0 + (u << 4)) * Nq + oo];
    }
#pragma unroll
    for (int u = 0; u < 4; ++u) {
        *(uint4*)&A_lds[(r0 + (u << 4)) * LDA + oo] = ra[u];
        *(uint4*)&P_lds[(r0 + (u << 4)) * LDA + oo] = rp[u];
    }
    __syncthreads();

    f32x4 acc[4] = {fzero(), fzero(), fzero(), fzero()};
    int brow = lane & 15, ko = (lane >> 4) << 3;
    const unsigned short* Afr = &A_lds[((w << 4) + brow) * LDA + ko];

    for (int kt = 0; kt < 8; ++kt) {
        if (kt < 7) {
            int j = (kt + 1) << 7;
#pragma unroll
            for (int u = 0; u < 4; ++u) {
                ra[u] = *(const uint4*)&Ag[(size_t)(r0 + (u << 4)) * Nq + j + oo];
                rp[u] = *(const uint4*)&Pg[(size_t)(r0 + (u << 4)) * Nq + j + oo];
            }
        }
#pragma unroll
        for (int ks = 0; ks < 4; ++ks) {
            bf16x8 af = *(const bf16x8*)(Afr + (ks << 5));
#pragma unroll
            for (int nt = 0; nt < 4; ++nt) {
                bf16x8 bfv = *(const bf16x8*)&P_lds[((nt << 4) + brow) * LDA + (ks << 5) + ko];
                acc[nt] = __builtin_amdgcn_mfma_f32_16x16x32_bf16(af, bfv, acc[nt], 0, 0, 0);
            }
        }
        __syncthreads();
        if (kt < 7) {
#pragma unroll
            for (int u = 0; u < 4; ++u) {
                *(uint4*)&A_lds[(r0 + (u << 4)) * LDA + oo] = ra[u];
                *(uint4*)&P_lds[(r0 + (u << 4)) * LDA + oo] = rp[u];
            }
            __syncthreads();
        }
    }
    // acc: Pn[row n=(w<<4)+(lane>>4)*4+r][col d=(nt<<4)+(lane&15)]
    int nrow = (w << 4) + ((lane >> 4) << 2);
    int dcol = lane & 15;
    if (writeP) {
#pragma unroll
        for (int nt = 0; nt < 4; ++nt) {
            uint2 pk = make_uint2(
                (unsigned)f2bf(acc[nt][0]) | ((unsigned)f2bf(acc[nt][1]) << 16),
                (unsigned)f2bf(acc[nt][2]) | ((unsigned)f2bf(acc[nt][3]) << 16));
            *(uint2*)&Ptout[(size_t)bh * DHq * Nq + (size_t)((nt << 4) + dcol) * Nq + n0 + nrow] = pk;
        }
    }
    // Pn -> LDS [n][d] (A-operand layout for the filter GEMM); reuse A_lds/P_lds
    unsigned short* PnL = A_lds;
    unsigned short* WtL = P_lds;
#pragma unroll
    for (int nt = 0; nt < 4; ++nt)
#pragma unroll
        for (int r = 0; r < 4; ++r)
            PnL[(nrow + r) * LDW + (nt << 4) + dcol] = f2bf(acc[nt][r]);
    const float* Wg = W_filt + ((size_t)h * (KH + 1) + khop) * DHq * DHq;
    for (int u = tid; u < 1024; u += 256) {
        int d = u >> 4, e4 = (u & 15) << 2;
        float4 wv = *(const float4*)&Wg[d * 64 + e4];
        WtL[(e4 + 0) * LDW + d] = f2bf(wv.x);
        WtL[(e4 + 1) * LDW + d] = f2bf(wv.y);
        WtL[(e4 + 2) * LDW + d] = f2bf(wv.z);
        WtL[(e4 + 3) * LDW + d] = f2bf(wv.w);
    }
    __syncthreads();
    f32x4 hacc[4] = {fzero(), fzero(), fzero(), fzero()};
    const unsigned short* Pfr = &PnL[((w << 4) + brow) * LDW + ko];
#pragma unroll
    for (int ks = 0; ks < 2; ++ks) {
        bf16x8 af = *(const bf16x8*)(Pfr + (ks << 5));
#pragma unroll
        for (int nt = 0; nt < 4; ++nt) {
            bf16x8 bfv = *(const bf16x8*)&WtL[((nt << 4) + brow) * LDW + (ks << 5) + ko];
            hacc[nt] = __builtin_amdgcn_mfma_f32_16x16x32_bf16(af, bfv, hacc[nt], 0, 0, 0);
        }
    }
    float av = alpha[h * (KH + 1) + khop];
    float* Ho = Hacc + ((size_t)b * Nq + n0 + nrow) * Dq + h * DHq;
#pragma unroll
    for (int nt = 0; nt < 4; ++nt)
#pragma unroll
        for (int r = 0; r < 4; ++r) {
            float* p = Ho + (size_t)r * Dq + (nt << 4) + dcol;
            *p += av * hacc[nt][r];
        }
}

// out = Hacc @ W_proj^T + b  (f32 inputs cast to bf16 during staging, MFMA, f32 out)
__global__ __launch_bounds__(256) void proj_mfma(const float* __restrict__ Hacc,
                                                 const float* __restrict__ Wp,
                                                 const float* __restrict__ bp,
                                                 float* __restrict__ out) {
    __shared__ unsigned short Hl[64 * LDA], Wl[64 * LDA];
    int tid = threadIdx.x, lane = tid & 63, w = tid >> 6;
    int i0 = blockIdx.y << 6, j0 = blockIdx.x << 6;
    f32x4 acc[4] = {fzero(), fzero(), fzero(), fzero()};
    int brow = lane & 15, ko = (lane >> 4) << 3;
    for (int kt = 0; kt < 4; ++kt) {
#pragma unroll
        for (int u = 0; u < 8; ++u) {
            int c = tid + (u << 8);
            int r = c >> 5, o4 = (c & 31) << 2;
            float4 hv = *(const float4*)&Hacc[(size_t)(i0 + r) * Dq + (kt << 7) + o4];
            *(uint2*)&Hl[r * LDA + o4] = pack4(hv);
            float4 wv = *(const float4*)&Wp[(size_t)(j0 + r) * Dq + (kt << 7) + o4];
            *(uint2*)&Wl[r * LDA + o4] = pack4(wv);
        }
        __syncthreads();
        const unsigned short* Afr = &Hl[((w << 4) + brow) * LDA + ko];
#pragma unroll
        for (int ks = 0; ks < 4; ++ks) {
            bf16x8 af = *(const bf16x8*)(Afr + (ks << 5));
#pragma unroll
            for (int nt = 0; nt < 4; ++nt) {
                bf16x8 bfv = *(const bf16x8*)&Wl[((nt << 4) + brow) * LDA + (ks << 5) + ko];
                acc[nt] = __builtin_amdgcn_mfma_f32_16x16x32_bf16(af, bfv, acc[nt], 0, 0, 0);
            }
        }
        __syncthreads();
    }
    int nrow = (w << 4) + ((lane >> 4) << 2);
#pragma unroll
    for (int nt = 0; nt < 4; ++nt) {
        float bb = bp[j0 + (nt << 4) + brow];
#pragma unroll
        for (int r = 0; r < 4; ++r)
            out[(size_t)(i0 + nrow + r) * Dq + j0 + (nt << 4) + brow] = acc[nt][r] + bb;
    }
}

// ---------------- launch ----------------

extern "C" void kernel_launch(void* const* d_in, const int* in_sizes, int n_in,
                              void* d_out, int out_size, void* d_ws, size_t ws_size,
                              hipStream_t stream) {
    (void)in_sizes; (void)n_in; (void)out_size; (void)ws_size;
    const float* X           = (const float*)d_in[0];
    const float* temperature = (const float*)d_in[1];
    const float* W_filt      = (const float*)d_in[2];
    const float* alpha       = (const float*)d_in[3];
    const float* W_proj      = (const float*)d_in[4];
    const float* b_proj      = (const float*)d_in[5];
    const int*   layer_idx   = (const int*)d_in[6];
    const int*   Lp          = (const int*)d_in[7];
    float* out = (float*)d_out;

    unsigned short* Sbf = (unsigned short*)d_ws;                    // 32*1024*1024 bf16 = 64 MiB
    unsigned short* Xn  = Sbf + (size_t)NBH * Nq * Nq;              // [32][1024][64]
    unsigned short* Xt  = Xn  + (size_t)NBH * Nq * DHq;             // [32][64][1024]
    unsigned short* Pt1 = Xt  + (size_t)NBH * DHq * Nq;             // [32][64][1024]
    unsigned short* Pt2 = Pt1 + (size_t)NBH * DHq * Nq;             // [32][64][1024]
    float* Hacc = (float*)(Pt2 + (size_t)NBH * DHq * Nq);           // [4][1024][512] f32

    dim3 blk(256);
    xcast_kernel<<<dim3(16, 32), blk, 0, stream>>>(X, Xn, Xt);
    score_mfma<<<dim3(16, 16, 32), blk, 0, stream>>>(Xn, temperature, Sbf);
    topk_softmax_kernel<<<dim3(NBH * Nq / 4), blk, 0, stream>>>(Sbf, layer_idx, Lp);

    filt0_mfma<<<dim3(16, 32), blk, 0, stream>>>(Xn, W_filt, alpha, Hacc);
    // hop 1: Pn = A @ Xh  (Pprev^T = Xt); write Pt1; Hacc += a1 * Pn@W1
    apf_mfma<<<dim3(16, 32), blk, 0, stream>>>(Sbf, Xt, Pt1, 1, W_filt, alpha, Hacc, 1);
    // hop 2
    apf_mfma<<<dim3(16, 32), blk, 0, stream>>>(Sbf, Pt1, Pt2, 1, W_filt, alpha, Hacc, 2);
    // hop 3 (no P write)
    apf_mfma<<<dim3(16, 32), blk, 0, stream>>>(Sbf, Pt2, Pt1, 0, W_filt, alpha, Hacc, 3);

    proj_mfma<<<dim3(8, 64), blk, 0, stream>>>(Hacc, W_proj, b_proj, out);
}

// Round 4
// 224.789 us; speedup vs baseline: 4.5665x; 1.4803x over previous
//
#include <hip/hip_runtime.h>
#include <math.h>

// Problem constants
#define Nq   1024
#define Dq   512
#define Hq   8
#define KH   3
#define DHq  64
#define NBH  32

typedef __attribute__((ext_vector_type(8))) __bf16 bf16x8;
typedef __attribute__((ext_vector_type(4))) float f32x4;

#define LDA 136   // LDS row stride (ushorts) for 128-wide K tiles (272 B = 17*16)
#define LDW 72    // LDS row stride (ushorts) for 64-wide K tiles (144 B = 9*16)

// ---------------- helpers ----------------

__device__ __forceinline__ unsigned short f2bf(float f) {  // RNE f32->bf16
    unsigned int u = __float_as_uint(f);
    u += 0x7FFFu + ((u >> 16) & 1u);
    return (unsigned short)(u >> 16);
}
__device__ __forceinline__ float bf2f(unsigned short b) {
    return __uint_as_float(((unsigned int)b) << 16);
}
// monotone 16-bit key for bf16 bit pattern
__device__ __forceinline__ unsigned key16(unsigned int b) {
    return (b & 0x8000u) ? (0xFFFFu & ~b) : (b | 0x8000u);
}
__device__ __forceinline__ uint2 pack4(float4 v) {
    return make_uint2((unsigned)f2bf(v.x) | ((unsigned)f2bf(v.y) << 16),
                      (unsigned)f2bf(v.z) | ((unsigned)f2bf(v.w) << 16));
}
__device__ __forceinline__ f32x4 fzero() { f32x4 z = {0.f, 0.f, 0.f, 0.f}; return z; }

// MFMA fragment addressing (16x16x32 bf16):
//  A-frag: lane l holds A[row=l&15][k=(l>>4)*8 + j]  -> row-major [m][k] LDS, b128 read
//  B-frag: lane l holds B[k=(l>>4)*8 + j][col=l&15]  -> store as [col][k] LDS, same read formula
//  C/D:    reg r -> C[row=(l>>4)*4+r][col=l&15]

// ---------------- kernels ----------------

// X f32 -> Xn bf16 [bh][1024][64] (n-major) and Xt bf16 [bh][64][1024] (d-major)
__global__ __launch_bounds__(256) void xcast_kernel(const float* __restrict__ X,
                                                    unsigned short* __restrict__ Xn,
                                                    unsigned short* __restrict__ Xt) {
    __shared__ float T[64][68];
    int tid = threadIdx.x;
    int bh = blockIdx.y, b = bh >> 3, h = bh & 7;
    int n0 = blockIdx.x << 6;
    const float* Xg = X + ((size_t)b * Nq + n0) * Dq + h * DHq;
#pragma unroll
    for (int u = 0; u < 4; ++u) {
        int idx = tid + (u << 8);
        int r = idx >> 4, c4 = (idx & 15) << 2;
        float4 v = *(const float4*)&Xg[(size_t)r * Dq + c4];
        *(uint2*)&Xn[((size_t)bh * Nq + n0 + r) * DHq + c4] = pack4(v);
        T[c4 + 0][r] = v.x; T[c4 + 1][r] = v.y; T[c4 + 2][r] = v.z; T[c4 + 3][r] = v.w;
    }
    __syncthreads();
#pragma unroll
    for (int u = 0; u < 4; ++u) {
        int idx = tid + (u << 8);
        int d = idx >> 4, n4 = (idx & 15) << 2;
        float4 v = make_float4(T[d][n4], T[d][n4 + 1], T[d][n4 + 2], T[d][n4 + 3]);
        *(uint2*)&Xt[((size_t)bh * DHq + d) * Nq + n0 + n4] = pack4(v);
    }
}

// S[bh,i,j] = dot(Xh[i],Xh[j]) / (8*clip(tau)), bf16 MFMA, S stored bf16
__global__ __launch_bounds__(256) void score_mfma(const unsigned short* __restrict__ Xn,
                                                  const float* __restrict__ temperature,
                                                  unsigned short* __restrict__ Sbf) {
    __shared__ unsigned short Xi[64 * LDW], Xj[64 * LDW];
    int tid = threadIdx.x, lane = tid & 63, w = tid >> 6;
    int bh = blockIdx.z, i0 = blockIdx.y << 6, j0 = blockIdx.x << 6;
    const unsigned short* Xb = Xn + (size_t)bh * Nq * DHq;
    {
        int row = tid >> 3, o = (tid & 7) << 3;
#pragma unroll
        for (int u = 0; u < 2; ++u) {
            int r = row + (u << 5);
            *(uint4*)&Xi[r * LDW + o] = *(const uint4*)&Xb[(size_t)(i0 + r) * DHq + o];
            *(uint4*)&Xj[r * LDW + o] = *(const uint4*)&Xb[(size_t)(j0 + r) * DHq + o];
        }
    }
    __syncthreads();
    f32x4 acc[4] = {fzero(), fzero(), fzero(), fzero()};
    int brow = lane & 15, ko = (lane >> 4) << 3;
    const unsigned short* Afr = &Xi[((w << 4) + brow) * LDW + ko];
#pragma unroll
    for (int ks = 0; ks < 2; ++ks) {
        bf16x8 af = *(const bf16x8*)(Afr + (ks << 5));
#pragma unroll
        for (int nt = 0; nt < 4; ++nt) {
            bf16x8 bfv = *(const bf16x8*)&Xj[((nt << 4) + brow) * LDW + (ks << 5) + ko];
            acc[nt] = __builtin_amdgcn_mfma_f32_16x16x32_bf16(af, bfv, acc[nt], 0, 0, 0);
        }
    }
    float tau = fminf(fmaxf(temperature[bh & 7], 0.1f), 5.0f);
    float inv = 1.0f / (8.0f * tau);
    int nrow = (w << 4) + ((lane >> 4) << 2);
    unsigned short* Sp = Sbf + ((size_t)bh * Nq + i0 + nrow) * Nq + j0;
#pragma unroll
    for (int nt = 0; nt < 4; ++nt)
#pragma unroll
        for (int r = 0; r < 4; ++r)
            Sp[(size_t)r * Nq + (nt << 4) + brow] = f2bf(acc[nt][r] * inv);
}

// One row per wave: exact k-th-largest via register-only binary search on 16-bit
// bf16 keys (ballot+popcount counting), then masked softmax. bf16 in/out in place.
__global__ __launch_bounds__(256) void topk_softmax_kernel(unsigned short* __restrict__ Sbf,
                                                           const int* __restrict__ layer_idx,
                                                           const int* __restrict__ Lptr) {
    int tid = threadIdx.x;
    int w = tid >> 6, lane = tid & 63;
    unsigned short* Srow = Sbf + ((size_t)blockIdx.x * 4 + w) * Nq;
    uint4 q0 = ((const uint4*)Srow)[lane * 2];
    uint4 q1 = ((const uint4*)Srow)[lane * 2 + 1];
    float v[16]; unsigned int k16[16];
    {
        unsigned int ww[8] = {q0.x, q0.y, q0.z, q0.w, q1.x, q1.y, q1.z, q1.w};
#pragma unroll
        for (int i = 0; i < 8; ++i) {
            unsigned lo16 = ww[i] & 0xFFFFu, hi16 = ww[i] >> 16;
            v[2 * i]     = __uint_as_float(lo16 << 16);
            v[2 * i + 1] = __uint_as_float(hi16 << 16);
            k16[2 * i]     = key16(lo16);
            k16[2 * i + 1] = key16(hi16);
        }
    }

    double sp = 0.8 + (0.2 - 0.8) * exp(-3.0 * (double)layer_idx[0] / (double)Lptr[0]);
    int kv = (int)((1.0 - sp) * (double)Nq);
    if (kv < 1) kv = 1;

    unsigned int tk = 0;
    if (kv < Nq) {
        unsigned int lo = 0;
#pragma unroll
        for (int bit = 15; bit >= 0; --bit) {
            unsigned int t = lo | (1u << bit);
            int cnt = 0;
#pragma unroll
            for (int i = 0; i < 16; ++i)
                cnt += (int)__popcll(__ballot(k16[i] >= t));
            if (cnt >= kv) lo = t;   // uniform across wave
        }
        tk = lo;  // exact 16-bit key of the k-th largest value in this row
    }

    float m = v[0];
#pragma unroll
    for (int i = 1; i < 16; ++i) m = fmaxf(m, v[i]);
#pragma unroll
    for (int off = 32; off; off >>= 1) m = fmaxf(m, __shfl_xor(m, off));
    float sum = 0.f;
#pragma unroll
    for (int i = 0; i < 16; ++i) {
        float e = (k16[i] >= tk) ? __expf(v[i] - m) : 0.0f;
        v[i] = e; sum += e;
    }
#pragma unroll
    for (int off = 32; off; off >>= 1) sum += __shfl_xor(sum, off);
    float inv = 1.0f / sum;
    unsigned int ow[8];
#pragma unroll
    for (int i = 0; i < 8; ++i)
        ow[i] = (unsigned)f2bf(v[2 * i] * inv) | ((unsigned)f2bf(v[2 * i + 1] * inv) << 16);
    ((uint4*)Srow)[lane * 2]     = make_uint4(ow[0], ow[1], ow[2], ow[3]);
    ((uint4*)Srow)[lane * 2 + 1] = make_uint4(ow[4], ow[5], ow[6], ow[7]);
}

// hop 0: Hacc = alpha[h,0] * (Xh @ W_filt[h,0])  via MFMA (initializes Hacc)
__global__ __launch_bounds__(256) void filt0_mfma(const unsigned short* __restrict__ Xn,
                                                  const float* __restrict__ W_filt,
                                                  const float* __restrict__ alpha,
                                                  float* __restrict__ Hacc) {
    __shared__ unsigned short PnL[64 * LDW], WtL[64 * LDW];
    int tid = threadIdx.x, lane = tid & 63, w = tid >> 6;
    int bh = blockIdx.y, b = bh >> 3, h = bh & 7;
    int n0 = blockIdx.x << 6;
    {
        int row = tid >> 3, o = (tid & 7) << 3;
        const unsigned short* Xb = Xn + ((size_t)bh * Nq + n0) * DHq;
#pragma unroll
        for (int u = 0; u < 2; ++u) {
            int r = row + (u << 5);
            *(uint4*)&PnL[r * LDW + o] = *(const uint4*)&Xb[(size_t)r * DHq + o];
        }
    }
    const float* Wg = W_filt + (size_t)h * (KH + 1) * DHq * DHq;
    for (int u = tid; u < 1024; u += 256) {
        int d = u >> 4, e4 = (u & 15) << 2;
        float4 wv = *(const float4*)&Wg[d * 64 + e4];
        WtL[(e4 + 0) * LDW + d] = f2bf(wv.x);
        WtL[(e4 + 1) * LDW + d] = f2bf(wv.y);
        WtL[(e4 + 2) * LDW + d] = f2bf(wv.z);
        WtL[(e4 + 3) * LDW + d] = f2bf(wv.w);
    }
    __syncthreads();
    f32x4 acc[4] = {fzero(), fzero(), fzero(), fzero()};
    int brow = lane & 15, ko = (lane >> 4) << 3;
    const unsigned short* Afr = &PnL[((w << 4) + brow) * LDW + ko];
#pragma unroll
    for (int ks = 0; ks < 2; ++ks) {
        bf16x8 af = *(const bf16x8*)(Afr + (ks << 5));
#pragma unroll
        for (int nt = 0; nt < 4; ++nt) {
            bf16x8 bfv = *(const bf16x8*)&WtL[((nt << 4) + brow) * LDW + (ks << 5) + ko];
            acc[nt] = __builtin_amdgcn_mfma_f32_16x16x32_bf16(af, bfv, acc[nt], 0, 0, 0);
        }
    }
    float av = alpha[h * (KH + 1)];
    int nrow = (w << 4) + ((lane >> 4) << 2);
    float* Ho = Hacc + ((size_t)b * Nq + n0 + nrow) * Dq + h * DHq;
#pragma unroll
    for (int nt = 0; nt < 4; ++nt)
#pragma unroll
        for (int r = 0; r < 4; ++r)
            Ho[(size_t)r * Dq + (nt << 4) + brow] = av * acc[nt][r];
}

// Fused hop: Pn = A @ Pprev; optionally write Pn^T bf16; then
// Hacc += alpha[h,khop] * Pn @ W_filt[h,khop].
// Double-buffered LDS: one barrier per K-step (grid = 2 blocks/CU, LDS is free).
__global__ __launch_bounds__(256) void apf_mfma(const unsigned short* __restrict__ Abf,
                                                const unsigned short* __restrict__ Ptin,
                                                unsigned short* __restrict__ Ptout, int writeP,
                                                const float* __restrict__ W_filt,
                                                const float* __restrict__ alpha,
                                                float* __restrict__ Hacc, int khop) {
    __shared__ unsigned short A_lds[2][64 * LDA];
    __shared__ unsigned short P_lds[2][64 * LDA];
    int tid = threadIdx.x, lane = tid & 63, w = tid >> 6;
    int bh = blockIdx.y, b = bh >> 3, h = bh & 7;
    int n0 = blockIdx.x << 6;
    const unsigned short* Ag = Abf + ((size_t)bh * Nq + n0) * Nq;
    const unsigned short* Pg = Ptin + (size_t)bh * DHq * Nq;
    int r0 = tid >> 4, oo = (tid & 15) << 3;

    uint4 ra[4], rp[4];
#pragma unroll
    for (int u = 0; u < 4; ++u) {
        ra[u] = *(const uint4*)&Ag[(size_t)(r0 + (u << 4)) * Nq + oo];
        rp[u] = *(const uint4*)&Pg[(size_t)(r0 + (u << 4)) * Nq + oo];
    }
#pragma unroll
    for (int u = 0; u < 4; ++u) {
        *(uint4*)&A_lds[0][(r0 + (u << 4)) * LDA + oo] = ra[u];
        *(uint4*)&P_lds[0][(r0 + (u << 4)) * LDA + oo] = rp[u];
    }
    __syncthreads();

    f32x4 acc[4] = {fzero(), fzero(), fzero(), fzero()};
    int brow = lane & 15, ko = (lane >> 4) << 3;
    int cur = 0;

    for (int kt = 0; kt < 8; ++kt) {
        if (kt < 7) {  // issue next-slice loads; latency hides under the MFMAs
            int j = (kt + 1) << 7;
#pragma unroll
            for (int u = 0; u < 4; ++u) {
                ra[u] = *(const uint4*)&Ag[(size_t)(r0 + (u << 4)) * Nq + j + oo];
                rp[u] = *(const uint4*)&Pg[(size_t)(r0 + (u << 4)) * Nq + j + oo];
            }
        }
        const unsigned short* Afr = &A_lds[cur][((w << 4) + brow) * LDA + ko];
#pragma unroll
        for (int ks = 0; ks < 4; ++ks) {
            bf16x8 af = *(const bf16x8*)(Afr + (ks << 5));
#pragma unroll
            for (int nt = 0; nt < 4; ++nt) {
                bf16x8 bfv = *(const bf16x8*)&P_lds[cur][((nt << 4) + brow) * LDA + (ks << 5) + ko];
                acc[nt] = __builtin_amdgcn_mfma_f32_16x16x32_bf16(af, bfv, acc[nt], 0, 0, 0);
            }
        }
        if (kt < 7) {  // write into the other buffer: no WAR hazard, one barrier
#pragma unroll
            for (int u = 0; u < 4; ++u) {
                *(uint4*)&A_lds[cur ^ 1][(r0 + (u << 4)) * LDA + oo] = ra[u];
                *(uint4*)&P_lds[cur ^ 1][(r0 + (u << 4)) * LDA + oo] = rp[u];
            }
        }
        __syncthreads();
        cur ^= 1;
    }

    // acc: Pn[row n=(w<<4)+(lane>>4)*4+r][col d=(nt<<4)+(lane&15)]
    int nrow = (w << 4) + ((lane >> 4) << 2);
    int dcol = lane & 15;
    if (writeP) {
#pragma unroll
        for (int nt = 0; nt < 4; ++nt) {
            uint2 pk = make_uint2(
                (unsigned)f2bf(acc[nt][0]) | ((unsigned)f2bf(acc[nt][1]) << 16),
                (unsigned)f2bf(acc[nt][2]) | ((unsigned)f2bf(acc[nt][3]) << 16));
            *(uint2*)&Ptout[(size_t)bh * DHq * Nq + (size_t)((nt << 4) + dcol) * Nq + n0 + nrow] = pk;
        }
    }
    // Pn -> LDS [n][d] (A-operand layout for the filter GEMM); reuse buffers
    unsigned short* PnL = &A_lds[0][0];
    unsigned short* WtL = &P_lds[0][0];
#pragma unroll
    for (int nt = 0; nt < 4; ++nt)
#pragma unroll
        for (int r = 0; r < 4; ++r)
            PnL[(nrow + r) * LDW + (nt << 4) + dcol] = f2bf(acc[nt][r]);
    const float* Wg = W_filt + ((size_t)h * (KH + 1) + khop) * DHq * DHq;
    for (int u = tid; u < 1024; u += 256) {
        int d = u >> 4, e4 = (u & 15) << 2;
        float4 wv = *(const float4*)&Wg[d * 64 + e4];
        WtL[(e4 + 0) * LDW + d] = f2bf(wv.x);
        WtL[(e4 + 1) * LDW + d] = f2bf(wv.y);
        WtL[(e4 + 2) * LDW + d] = f2bf(wv.z);
        WtL[(e4 + 3) * LDW + d] = f2bf(wv.w);
    }
    __syncthreads();
    f32x4 hacc[4] = {fzero(), fzero(), fzero(), fzero()};
    const unsigned short* Pfr = &PnL[((w << 4) + brow) * LDW + ko];
#pragma unroll
    for (int ks = 0; ks < 2; ++ks) {
        bf16x8 af = *(const bf16x8*)(Pfr + (ks << 5));
#pragma unroll
        for (int nt = 0; nt < 4; ++nt) {
            bf16x8 bfv = *(const bf16x8*)&WtL[((nt << 4) + brow) * LDW + (ks << 5) + ko];
            hacc[nt] = __builtin_amdgcn_mfma_f32_16x16x32_bf16(af, bfv, hacc[nt], 0, 0, 0);
        }
    }
    float av = alpha[h * (KH + 1) + khop];
    float* Ho = Hacc + ((size_t)b * Nq + n0 + nrow) * Dq + h * DHq;
#pragma unroll
    for (int nt = 0; nt < 4; ++nt)
#pragma unroll
        for (int r = 0; r < 4; ++r) {
            float* p = Ho + (size_t)r * Dq + (nt << 4) + dcol;
            *p += av * hacc[nt][r];
        }
}

// out = Hacc @ W_proj^T + b  (f32 inputs cast to bf16 during staging, MFMA, f32 out)
__global__ __launch_bounds__(256) void proj_mfma(const float* __restrict__ Hacc,
                                                 const float* __restrict__ Wp,
                                                 const float* __restrict__ bp,
                                                 float* __restrict__ out) {
    __shared__ unsigned short Hl[64 * LDA], Wl[64 * LDA];
    int tid = threadIdx.x, lane = tid & 63, w = tid >> 6;
    int i0 = blockIdx.y << 6, j0 = blockIdx.x << 6;
    f32x4 acc[4] = {fzero(), fzero(), fzero(), fzero()};
    int brow = lane & 15, ko = (lane >> 4) << 3;
    for (int kt = 0; kt < 4; ++kt) {
#pragma unroll
        for (int u = 0; u < 8; ++u) {
            int c = tid + (u << 8);
            int r = c >> 5, o4 = (c & 31) << 2;
            float4 hv = *(const float4*)&Hacc[(size_t)(i0 + r) * Dq + (kt << 7) + o4];
            *(uint2*)&Hl[r * LDA + o4] = pack4(hv);
            float4 wv = *(const float4*)&Wp[(size_t)(j0 + r) * Dq + (kt << 7) + o4];
            *(uint2*)&Wl[r * LDA + o4] = pack4(wv);
        }
        __syncthreads();
        const unsigned short* Afr = &Hl[((w << 4) + brow) * LDA + ko];
#pragma unroll
        for (int ks = 0; ks < 4; ++ks) {
            bf16x8 af = *(const bf16x8*)(Afr + (ks << 5));
#pragma unroll
            for (int nt = 0; nt < 4; ++nt) {
                bf16x8 bfv = *(const bf16x8*)&Wl[((nt << 4) + brow) * LDA + (ks << 5) + ko];
                acc[nt] = __builtin_amdgcn_mfma_f32_16x16x32_bf16(af, bfv, acc[nt], 0, 0, 0);
            }
        }
        __syncthreads();
    }
    int nrow = (w << 4) + ((lane >> 4) << 2);
#pragma unroll
    for (int nt = 0; nt < 4; ++nt) {
        float bb = bp[j0 + (nt << 4) + brow];
#pragma unroll
        for (int r = 0; r < 4; ++r)
            out[(size_t)(i0 + nrow + r) * Dq + j0 + (nt << 4) + brow] = acc[nt][r] + bb;
    }
}

// ---------------- launch ----------------

extern "C" void kernel_launch(void* const* d_in, const int* in_sizes, int n_in,
                              void* d_out, int out_size, void* d_ws, size_t ws_size,
                              hipStream_t stream) {
    (void)in_sizes; (void)n_in; (void)out_size; (void)ws_size;
    const float* X           = (const float*)d_in[0];
    const float* temperature = (const float*)d_in[1];
    const float* W_filt      = (const float*)d_in[2];
    const float* alpha       = (const float*)d_in[3];
    const float* W_proj      = (const float*)d_in[4];
    const float* b_proj      = (const float*)d_in[5];
    const int*   layer_idx   = (const int*)d_in[6];
    const int*   Lp          = (const int*)d_in[7];
    float* out = (float*)d_out;

    unsigned short* Sbf = (unsigned short*)d_ws;                    // 32*1024*1024 bf16 = 64 MiB
    unsigned short* Xn  = Sbf + (size_t)NBH * Nq * Nq;              // [32][1024][64]
    unsigned short* Xt  = Xn  + (size_t)NBH * Nq * DHq;             // [32][64][1024]
    unsigned short* Pt1 = Xt  + (size_t)NBH * DHq * Nq;             // [32][64][1024]
    unsigned short* Pt2 = Pt1 + (size_t)NBH * DHq * Nq;             // [32][64][1024]
    float* Hacc = (float*)(Pt2 + (size_t)NBH * DHq * Nq);           // [4][1024][512] f32

    dim3 blk(256);
    xcast_kernel<<<dim3(16, 32), blk, 0, stream>>>(X, Xn, Xt);
    score_mfma<<<dim3(16, 16, 32), blk, 0, stream>>>(Xn, temperature, Sbf);
    topk_softmax_kernel<<<dim3(NBH * Nq / 4), blk, 0, stream>>>(Sbf, layer_idx, Lp);

    filt0_mfma<<<dim3(16, 32), blk, 0, stream>>>(Xn, W_filt, alpha, Hacc);
    // hop 1: Pn = A @ Xh  (Pprev^T = Xt); write Pt1; Hacc += a1 * Pn@W1
    apf_mfma<<<dim3(16, 32), blk, 0, stream>>>(Sbf, Xt, Pt1, 1, W_filt, alpha, Hacc, 1);
    // hop 2
    apf_mfma<<<dim3(16, 32), blk, 0, stream>>>(Sbf, Pt1, Pt2, 1, W_filt, alpha, Hacc, 2);
    // hop 3 (no P write)
    apf_mfma<<<dim3(16, 32), blk, 0, stream>>>(Sbf, Pt2, Pt1, 0, W_filt, alpha, Hacc, 3);

    proj_mfma<<<dim3(8, 64), blk, 0, stream>>>(Hacc, W_proj, b_proj, out);
}